// Round 9
// baseline (273.685 us; speedup 1.0000x reference)
//
#include <hip/hip_runtime.h>
#include <math.h>

#define CH  1024
#define PPB 8192            // positions per batch (D*N = 64*128)

typedef __attribute__((ext_vector_type(8))) short short8;
typedef __attribute__((ext_vector_type(4))) float f32x4;

__device__ __forceinline__ ushort f2bf(float x) {
    uint u = __float_as_uint(x);
    return (ushort)((u + 0x7FFFu + ((u >> 16) & 1u)) >> 16);   // RNE
}
__device__ __forceinline__ float bf2f(ushort u) {
    return __uint_as_float(((uint)u) << 16);
}
__device__ __forceinline__ void gload16(const void* g, const void* l) {
    __builtin_amdgcn_global_load_lds((const __attribute__((address_space(1))) void*)g,
                                     (__attribute__((address_space(3))) void*)l, 16, 0, 0);
}

// ---------------------------------------------------------------------------
// Fused prep: [0,2048) weight fp32->bf16; [2048,6144) lidar transpose;
// [6144,10240) cam transpose.  transpose: in[b][c][p] f32 -> out[b][p][c] bf16
// ---------------------------------------------------------------------------
__global__ __launch_bounds__(256) void prep(const float* __restrict__ lidar,
                                            const float* __restrict__ cam,
                                            const float* __restrict__ Wq,
                                            const float* __restrict__ Wk,
                                            const float* __restrict__ Wv,
                                            const float* __restrict__ Wo,
                                            ushort* __restrict__ wdst,
                                            ushort* __restrict__ lidT,
                                            ushort* __restrict__ camT)
{
    __shared__ float T[64][65];
    const int blk = blockIdx.x;
    const int tid = threadIdx.x;

    if (blk < 2048) {      // ---- weight convert: 4 x 1M elems ----
        const int y = blk >> 9;
        const int x = blk & 511;
        const float* w = (y == 0) ? Wq : (y == 1) ? Wk : (y == 2) ? Wv : Wo;
        ushort* o = wdst + (size_t)y * (1u << 20);
        const int idx = (x * 256 + tid) * 8;
        const float4 v0 = *(const float4*)(w + idx);
        const float4 v1 = *(const float4*)(w + idx + 4);
        ushort4 o0, o1;
        o0.x = f2bf(v0.x); o0.y = f2bf(v0.y); o0.z = f2bf(v0.z); o0.w = f2bf(v0.w);
        o1.x = f2bf(v1.x); o1.y = f2bf(v1.y); o1.z = f2bf(v1.z); o1.w = f2bf(v1.w);
        *(ushort4*)(o + idx)     = o0;
        *(ushort4*)(o + idx + 4) = o1;
        return;
    }

    // ---- transpose+convert ----
    const int t = blk - 2048;
    const bool isLid = (t < 4096);
    const int tt = isLid ? t : t - 4096;
    const float* in = isLid ? lidar : cam;
    ushort* out = isLid ? lidT : camT;

    const int p0 = (tt & 127) * 64;
    const int c0 = ((tt >> 7) & 15) * 64;
    const int b  = tt >> 11;
    const int rc = tid >> 4;            // 0..15
    const int rp = (tid & 15) * 4;      // 0..60

    #pragma unroll
    for (int pass = 0; pass < 4; ++pass) {
        const int c = pass * 16 + rc;
        const size_t base = ((size_t)(b * CH + c0 + c)) * PPB + p0 + rp;
        const float4 v = *(const float4*)(in + base);
        T[c][rp] = v.x; T[c][rp + 1] = v.y; T[c][rp + 2] = v.z; T[c][rp + 3] = v.w;
    }
    __syncthreads();
    #pragma unroll
    for (int pass = 0; pass < 4; ++pass) {
        const int p = pass * 16 + rc;
        ushort4 o;
        o.x = f2bf(T[rp + 0][p]); o.y = f2bf(T[rp + 1][p]);
        o.z = f2bf(T[rp + 2][p]); o.w = f2bf(T[rp + 3][p]);
        *(ushort4*)(out + ((size_t)(b * PPB + p0 + p)) * CH + c0 + rp) = o;
    }
}

// ---------------------------------------------------------------------------
// bf16 transpose with attn-out remap: in[b][c][s] bf16 (s=i*64+d) ->
// out[b][d*128+i][c] bf16
// ---------------------------------------------------------------------------
__global__ __launch_bounds__(256) void transpose_ao(const ushort* __restrict__ in_,
                                                    ushort* __restrict__ out)
{
    __shared__ float T[64][65];
    const int p0 = blockIdx.x * 64;
    const int c0 = blockIdx.y * 64;
    const int b  = blockIdx.z;
    const int t  = threadIdx.x;
    const int rc = t >> 4;
    const int rp = (t & 15) * 4;

    #pragma unroll
    for (int pass = 0; pass < 4; ++pass) {
        const int c = pass * 16 + rc;
        const size_t base = ((size_t)(b * CH + c0 + c)) * PPB + p0 + rp;
        const ushort4 v = *(const ushort4*)(in_ + base);
        T[c][rp]     = bf2f(v.x); T[c][rp + 1] = bf2f(v.y);
        T[c][rp + 2] = bf2f(v.z); T[c][rp + 3] = bf2f(v.w);
    }
    __syncthreads();
    #pragma unroll
    for (int pass = 0; pass < 4; ++pass) {
        const int p = pass * 16 + rc;                    // tile-local s
        const int prow = p * 128 + blockIdx.x;           // s=i*64+d -> p=d*128+i
        ushort4 o;
        o.x = f2bf(T[rp + 0][p]); o.y = f2bf(T[rp + 1][p]);
        o.z = f2bf(T[rp + 2][p]); o.w = f2bf(T[rp + 3][p]);
        *(ushort4*)(out + ((size_t)(b * PPB + prow)) * CH + c0 + rp) = o;
    }
}

// ---------------------------------------------------------------------------
// 256x256 bf16 MFMA GEMM, BK=64, 8 waves (2M x 4N), wave tile 128x64,
// 16x16x32 fragments (r7-proven conflict-free swizzle & epilogue).
// R9 schedule: (1) DEEP counted vmcnt — all 4 half-tiles of kt+1 staged at
// tile top (WAR-safe: nxt fully read before end-of-(kt-1) barrier), then
// vmcnt(8): tile kt's loads (issued a full tile ago) are free, kt+1's 8
// loads stay in flight across all barriers (T4; m218 +38-73%).
// (2) Per-phase barrier pairs: 4 quadrant phases per tile, each
// {ds_read, lgkmcnt(0), setprio MFMA, s_barrier} — wave role-split so
// setprio pays (T5 gate; m196/m201 structure).
// IS_WO=0: 768 blocks, g=0:q(lidT,remap) 1:k(camT,remap) 2:v(camT,linear).
// IS_WO=1: 256 blocks, g=3, B linear, f32 gelu out. W3 = weight base (ws).
// ---------------------------------------------------------------------------
template <int IS_WO>
__global__ __launch_bounds__(512, 2) void gemm256(const ushort* __restrict__ W3,
                                                  const ushort* __restrict__ lidT,
                                                  const ushort* __restrict__ camT,
                                                  void* __restrict__ outp)
{
    __shared__ __align__(16) ushort sh[65536];  // [0,64K): A dbuf; [64K,128K): B dbuf
    char* shb = (char*)sh;

    const int bid = blockIdx.x;
    int g, bm, bn;
    if (IS_WO) {
        const int sid = (bid & 7) * 32 + (bid >> 3);   // 256 % 8 == 0, bijective
        g = 3; bm = sid & 3; bn = sid >> 2;
    } else {
        const int sid = (bid & 7) * 96 + (bid >> 3);   // 768 % 8 == 0, bijective
        g = sid >> 8; const int r = sid & 255; bm = r & 3; bn = r >> 2;
    }
    const int m0  = bm * 256;
    const int b   = bn >> 5;                // 64 n-tiles, 32 per batch
    const int nn0 = (bn & 31) * 4;          // q/k remap: 4 i-values per 256-tile
    const int n0  = bn * 256;               // linear B row base
    const ushort* A  = W3 + (size_t)g * (1u << 20);
    const ushort* Bt = (g == 0) ? lidT : camT;   // IS_WO: camT param carries aoT
    const bool remap = (!IS_WO) && (g < 2);

    const int tid = threadIdx.x;
    const int w   = tid >> 6;
    const int l   = tid & 63;
    const int wr  = w >> 2;       // 0..1  M half
    const int wc  = w & 3;        // 0..3  N quarter
    const int hi  = l >> 4;
    const int fr  = l & 15;

    // stage one 16KB half-tile (A or B) of K-tile kt into buffer buf.
    // dest linear; source chunk pre-swizzled: LDS[row][slot s] holds global
    // chunk s^(row&7)  (involution; read applies the same XOR).
    auto stageA = [&](int buf, int kt, int half) {
        const int k0 = kt * 64;
        #pragma unroll
        for (int ld = 0; ld < 2; ++ld) {
            const int c  = w * 2 + ld;                 // chunk 0..15 (8 rows each)
            const int rt = half * 128 + c * 8 + (l >> 3);
            const int kc = ((l & 7) ^ (rt & 7)) << 3;
            gload16(A + (size_t)(m0 + rt) * CH + k0 + kc,
                    &shb[buf * 32768 + half * 16384 + c * 1024]);
        }
    };
    auto stageB = [&](int buf, int kt, int half) {
        const int k0 = kt * 64;
        #pragma unroll
        for (int ld = 0; ld < 2; ++ld) {
            const int c  = w * 2 + ld;
            const int rt = half * 128 + c * 8 + (l >> 3);
            const int kc = ((l & 7) ^ (rt & 7)) << 3;
            size_t brow;
            if (remap) brow = (size_t)b * PPB + (size_t)(rt & 63) * 128 + nn0 + (rt >> 6);
            else       brow = (size_t)(n0 + rt);
            gload16(Bt + brow * CH + k0 + kc,
                    &shb[65536 + buf * 32768 + half * 16384 + c * 1024]);
        }
    };

    f32x4 acc[8][4];
    #pragma unroll
    for (int i = 0; i < 8; ++i)
        #pragma unroll
        for (int j = 0; j < 4; ++j) acc[i][j] = (f32x4)(0.0f);

    // prologue: tile 0, all 4 halves (8 vmem instructions)
    stageA(0, 0, 0); stageA(0, 0, 1); stageB(0, 0, 0); stageB(0, 0, 1);

    for (int kt = 0; kt < 16; ++kt) {
        const int buf = kt & 1, nxt = buf ^ 1;
        // EARLY stage of ALL tile kt+1 halves; counted wait leaves them in
        // flight for the entire tile-kt compute (never drain mid-loop).
        if (kt < 15) {
            stageA(nxt, kt + 1, 0); stageA(nxt, kt + 1, 1);
            stageB(nxt, kt + 1, 0); stageB(nxt, kt + 1, 1);
            __builtin_amdgcn_sched_barrier(0);
            asm volatile("s_waitcnt vmcnt(8)" ::: "memory");  // tile kt resident
        } else {
            __builtin_amdgcn_sched_barrier(0);
            asm volatile("s_waitcnt vmcnt(0)" ::: "memory");
        }
        __builtin_amdgcn_s_barrier();           // all waves' tile-kt loads landed
        __builtin_amdgcn_sched_barrier(0);
        const int Ab = buf * 32768, Bb = 65536 + buf * 32768;

        short8 aq[4][2], bq[2][2];
        auto LDA = [&](int mh) {
            #pragma unroll
            for (int fm = 0; fm < 4; ++fm) {
                const int row = wr * 128 + (mh * 4 + fm) * 16 + fr;
                #pragma unroll
                for (int kk = 0; kk < 2; ++kk)
                    aq[fm][kk] = *(const short8*)&shb[Ab + row * 128 +
                        ((((kk << 2) + hi) ^ (row & 7)) << 4)];
            }
        };
        auto LDB = [&](int nh) {
            #pragma unroll
            for (int fn = 0; fn < 2; ++fn) {
                const int row = wc * 64 + (nh * 2 + fn) * 16 + fr;
                #pragma unroll
                for (int kk = 0; kk < 2; ++kk)
                    bq[fn][kk] = *(const short8*)&shb[Bb + row * 128 +
                        ((((kk << 2) + hi) ^ (row & 7)) << 4)];
            }
        };
        auto MF = [&](int mh, int nh) {     // kk-outer: 8 independent per kk
            __builtin_amdgcn_s_setprio(1);
            #pragma unroll
            for (int kk = 0; kk < 2; ++kk)
                #pragma unroll
                for (int fm = 0; fm < 4; ++fm)
                    #pragma unroll
                    for (int fn = 0; fn < 2; ++fn)
                        acc[mh * 4 + fm][nh * 2 + fn] =
                            __builtin_amdgcn_mfma_f32_16x16x32_bf16(
                                aq[fm][kk], bq[fn][kk],
                                acc[mh * 4 + fm][nh * 2 + fn], 0, 0, 0);
            __builtin_amdgcn_s_setprio(0);
        };
        auto PHASE_END = [&]() {
            __builtin_amdgcn_sched_barrier(0);
            asm volatile("s_waitcnt lgkmcnt(0)" ::: "memory");
            __builtin_amdgcn_sched_barrier(0);
            __builtin_amdgcn_s_barrier();
            __builtin_amdgcn_sched_barrier(0);
        };

        // 4 quadrant phases, snake order with fragment reuse (28 b128/tile)
        LDA(0); LDB(0);
        __builtin_amdgcn_sched_barrier(0);
        asm volatile("s_waitcnt lgkmcnt(0)" ::: "memory");
        __builtin_amdgcn_sched_barrier(0);
        MF(0, 0); PHASE_END();
        LDB(1);
        __builtin_amdgcn_sched_barrier(0);
        asm volatile("s_waitcnt lgkmcnt(0)" ::: "memory");
        __builtin_amdgcn_sched_barrier(0);
        MF(0, 1); PHASE_END();
        LDA(1);
        __builtin_amdgcn_sched_barrier(0);
        asm volatile("s_waitcnt lgkmcnt(0)" ::: "memory");
        __builtin_amdgcn_sched_barrier(0);
        MF(1, 1); PHASE_END();
        LDB(0);
        __builtin_amdgcn_sched_barrier(0);
        asm volatile("s_waitcnt lgkmcnt(0)" ::: "memory");
        __builtin_amdgcn_sched_barrier(0);
        MF(1, 0); PHASE_END();   // final barrier = end-of-tile (WAR for stages)
    }

    // epilogue: C/D col=fr, row=hi*4+r (m89-verified)
    const int rq = hi;
    #pragma unroll
    for (int fm = 0; fm < 8; ++fm)
        #pragma unroll
        for (int fn = 0; fn < 4; ++fn)
            #pragma unroll
            for (int r = 0; r < 4; ++r) {
                const int m = m0 + wr * 128 + fm * 16 + rq * 4 + r;
                const int s = (bn & 31) * 256 + wc * 64 + fn * 16 + fr;
                const float vv = acc[fm][fn][r];
                const size_t off = (size_t)b * CH * PPB + (size_t)m * PPB + s;
                if (IS_WO) {
                    ((float*)outp)[off] = 0.5f * vv * (1.0f + erff(vv * 0.70710678118654752f));
                } else {
                    ((ushort*)outp)[(size_t)g * ((size_t)16 << 20) + off] = f2bf(vv);
                }
            }
}

// ---------------------------------------------------------------------------
// MFMA attention, one (b,h) per block, 4 waves (unchanged from rounds 3-7).
// ---------------------------------------------------------------------------
__global__ __launch_bounds__(256, 2) void attn_mfma(const ushort* __restrict__ qt,
                                                    const ushort* __restrict__ kt,
                                                    const ushort* __restrict__ vn,
                                                    ushort* __restrict__ ot)
{
    __shared__ ushort Qs[8192];
    __shared__ ushort Ks[8192];
    __shared__ ushort Vs[8192];
    __shared__ ushort Ps[16384];

    const int bh  = blockIdx.x;
    const int tid = threadIdx.x;
    const int w   = tid >> 6;
    const int l   = tid & 63;
    const int hi  = l >> 4;
    const int fr  = l & 15;
    const size_t base = (size_t)bh * 8192;

    {
        const int lr = l >> 3, lb = l & 7;
        const int vr = l >> 4, vbk = l & 15;
        #pragma unroll
        for (int q = 0; q < 4; ++q) {
            const int ch = w * 4 + q;
            const int i  = ch * 8 + lr;
            gload16(qt + base + i * 64 + ((lb ^ (i & 7)) << 3), &Qs[ch * 512]);
            gload16(kt + base + i * 64 + ((lb ^ (i & 7)) << 3), &Ks[ch * 512]);
            const int d  = ch * 4 + vr;
            gload16(vn + base + d * 128 + ((vbk ^ (d & 15)) << 3), &Vs[ch * 512]);
        }
    }
    __syncthreads();

    const int i0w = w * 32;
    f32x4 accS[2][8];
    #pragma unroll
    for (int a = 0; a < 2; ++a)
        #pragma unroll
        for (int bjj = 0; bjj < 8; ++bjj) accS[a][bjj] = (f32x4)(0.0f);

    #pragma unroll
    for (int kk = 0; kk < 2; ++kk) {
        const int blk = kk * 4 + hi;
        short8 aq[2];
        #pragma unroll
        for (int fm = 0; fm < 2; ++fm) {
            const int i = i0w + fm * 16 + fr;
            aq[fm] = *(const short8*)&Qs[i * 64 + ((blk ^ (i & 7)) << 3)];
        }
        #pragma unroll
        for (int fn = 0; fn < 8; ++fn) {
            const int j = fn * 16 + fr;
            const short8 bk = *(const short8*)&Ks[j * 64 + ((blk ^ (j & 7)) << 3)];
            #pragma unroll
            for (int fm = 0; fm < 2; ++fm)
                accS[fm][fn] = __builtin_amdgcn_mfma_f32_16x16x32_bf16(
                    aq[fm], bk, accS[fm][fn], 0, 0, 0);
        }
    }

    const float CS = 0.125f * 1.44269504088896341f;
    #pragma unroll
    for (int fm = 0; fm < 2; ++fm) {
        #pragma unroll
        for (int r = 0; r < 4; ++r) {
            float mx = accS[fm][0][r];
            #pragma unroll
            for (int fn = 1; fn < 8; ++fn) mx = fmaxf(mx, accS[fm][fn][r]);
            #pragma unroll
            for (int msk = 1; msk <= 8; msk <<= 1) mx = fmaxf(mx, __shfl_xor(mx, msk, 64));
            float e[8], sum = 0.f;
            #pragma unroll
            for (int fn = 0; fn < 8; ++fn) {
                e[fn] = exp2f((accS[fm][fn][r] - mx) * CS);
                sum += e[fn];
            }
            #pragma unroll
            for (int msk = 1; msk <= 8; msk <<= 1) sum += __shfl_xor(sum, msk, 64);
            const float is = 1.0f / sum;
            const int i = i0w + fm * 16 + hi * 4 + r;
            #pragma unroll
            for (int fn = 0; fn < 8; ++fn) {
                const int j = fn * 16 + fr;
                Ps[i * 128 + (((j >> 3) ^ (i & 15)) << 3) + (j & 7)] = f2bf(e[fn] * is);
            }
        }
    }

    f32x4 accO[2][4];
    #pragma unroll
    for (int a = 0; a < 2; ++a)
        #pragma unroll
        for (int bjj = 0; bjj < 4; ++bjj) accO[a][bjj] = (f32x4)(0.0f);

    #pragma unroll
    for (int ks2 = 0; ks2 < 4; ++ks2) {
        const int blk = ks2 * 4 + hi;
        short8 ap[2];
        #pragma unroll
        for (int fm = 0; fm < 2; ++fm) {
            const int i = i0w + fm * 16 + fr;
            ap[fm] = *(const short8*)&Ps[i * 128 + ((blk ^ (i & 15)) << 3)];
        }
        #pragma unroll
        for (int fn2 = 0; fn2 < 4; ++fn2) {
            const int d = fn2 * 16 + fr;
            const short8 bv = *(const short8*)&Vs[d * 128 + ((blk ^ (d & 15)) << 3)];
            #pragma unroll
            for (int fm = 0; fm < 2; ++fm)
                accO[fm][fn2] = __builtin_amdgcn_mfma_f32_16x16x32_bf16(
                    ap[fm], bv, accO[fm][fn2], 0, 0, 0);
        }
    }

    #pragma unroll
    for (int fm = 0; fm < 2; ++fm)
        #pragma unroll
        for (int fn2 = 0; fn2 < 4; ++fn2)
            #pragma unroll
            for (int r = 0; r < 4; ++r) {
                const int i = i0w + fm * 16 + hi * 4 + r;
                const int d = fn2 * 16 + fr;
                ot[base + i * 64 + d] = f2bf(accO[fm][fn2][r]);
            }
}

// ---------------------------------------------------------------------------
extern "C" void kernel_launch(void* const* d_in, const int* in_sizes, int n_in,
                              void* d_out, int out_size, void* d_ws, size_t ws_size,
                              hipStream_t stream)
{
    const float* lidar = (const float*)d_in[0];
    const float* cam   = (const float*)d_in[1];
    const float* Wq    = (const float*)d_in[2];
    const float* Wk    = (const float*)d_in[3];
    const float* Wv    = (const float*)d_in[4];
    const float* Wo    = (const float*)d_in[5];

    ushort* ws = (ushort*)d_ws;
    const size_t M1 = (size_t)1 << 20;
    const size_t TT = (size_t)16 << 20;
    ushort* lidT = ws + 4 * M1;
    ushort* camT = lidT + TT;
    ushort* qb   = camT + TT;   // q_t [b][c][i][d]; attn overwrites with O_t
    ushort* aoT  = lidT;        // reuse (lidT dead after q GEMM)

    prep<<<dim3(10240), dim3(256), 0, stream>>>(lidar, cam, Wq, Wk, Wv, Wo, ws, lidT, camT);

    gemm256<0><<<dim3(768), dim3(512), 0, stream>>>(ws, lidT, camT, qb);

    attn_mfma<<<dim3(2048), dim3(256), 0, stream>>>(qb, qb + TT, qb + 2 * TT, qb);

    transpose_ao<<<dim3(128, 16, 2), dim3(256), 0, stream>>>(qb, aoT);

    gemm256<1><<<dim3(256), dim3(512), 0, stream>>>(ws, aoT, aoT, (float*)d_out);
}

// Round 10
// 232.473 us; speedup vs baseline: 1.1773x; 1.1773x over previous
//
#include <hip/hip_runtime.h>
#include <math.h>

#define CH  1024
#define PPB 8192            // positions per batch (D*N = 64*128)

typedef __attribute__((ext_vector_type(8))) short short8;
typedef __attribute__((ext_vector_type(4))) float f32x4;

__device__ __forceinline__ ushort f2bf(float x) {
    uint u = __float_as_uint(x);
    return (ushort)((u + 0x7FFFu + ((u >> 16) & 1u)) >> 16);   // RNE
}
__device__ __forceinline__ float bf2f(ushort u) {
    return __uint_as_float(((uint)u) << 16);
}
__device__ __forceinline__ void gload16(const void* g, const void* l) {
    __builtin_amdgcn_global_load_lds((const __attribute__((address_space(1))) void*)g,
                                     (__attribute__((address_space(3))) void*)l, 16, 0, 0);
}

// ---------------------------------------------------------------------------
// Fused prep: [0,2048) weight fp32->bf16; [2048,6144) lidar transpose;
// [6144,10240) cam transpose.  transpose: in[b][c][p] f32 -> out[b][p][c] bf16
// ---------------------------------------------------------------------------
__global__ __launch_bounds__(256) void prep(const float* __restrict__ lidar,
                                            const float* __restrict__ cam,
                                            const float* __restrict__ Wq,
                                            const float* __restrict__ Wk,
                                            const float* __restrict__ Wv,
                                            const float* __restrict__ Wo,
                                            ushort* __restrict__ wdst,
                                            ushort* __restrict__ lidT,
                                            ushort* __restrict__ camT)
{
    __shared__ float T[64][65];
    const int blk = blockIdx.x;
    const int tid = threadIdx.x;

    if (blk < 2048) {      // ---- weight convert: 4 x 1M elems ----
        const int y = blk >> 9;
        const int x = blk & 511;
        const float* w = (y == 0) ? Wq : (y == 1) ? Wk : (y == 2) ? Wv : Wo;
        ushort* o = wdst + (size_t)y * (1u << 20);
        const int idx = (x * 256 + tid) * 8;
        const float4 v0 = *(const float4*)(w + idx);
        const float4 v1 = *(const float4*)(w + idx + 4);
        ushort4 o0, o1;
        o0.x = f2bf(v0.x); o0.y = f2bf(v0.y); o0.z = f2bf(v0.z); o0.w = f2bf(v0.w);
        o1.x = f2bf(v1.x); o1.y = f2bf(v1.y); o1.z = f2bf(v1.z); o1.w = f2bf(v1.w);
        *(ushort4*)(o + idx)     = o0;
        *(ushort4*)(o + idx + 4) = o1;
        return;
    }

    // ---- transpose+convert ----
    const int t = blk - 2048;
    const bool isLid = (t < 4096);
    const int tt = isLid ? t : t - 4096;
    const float* in = isLid ? lidar : cam;
    ushort* out = isLid ? lidT : camT;

    const int p0 = (tt & 127) * 64;
    const int c0 = ((tt >> 7) & 15) * 64;
    const int b  = tt >> 11;
    const int rc = tid >> 4;            // 0..15
    const int rp = (tid & 15) * 4;      // 0..60

    #pragma unroll
    for (int pass = 0; pass < 4; ++pass) {
        const int c = pass * 16 + rc;
        const size_t base = ((size_t)(b * CH + c0 + c)) * PPB + p0 + rp;
        const float4 v = *(const float4*)(in + base);
        T[c][rp] = v.x; T[c][rp + 1] = v.y; T[c][rp + 2] = v.z; T[c][rp + 3] = v.w;
    }
    __syncthreads();
    #pragma unroll
    for (int pass = 0; pass < 4; ++pass) {
        const int p = pass * 16 + rc;
        ushort4 o;
        o.x = f2bf(T[rp + 0][p]); o.y = f2bf(T[rp + 1][p]);
        o.z = f2bf(T[rp + 2][p]); o.w = f2bf(T[rp + 3][p]);
        *(ushort4*)(out + ((size_t)(b * PPB + p0 + p)) * CH + c0 + rp) = o;
    }
}

// ---------------------------------------------------------------------------
// bf16 transpose with attn-out remap: in[b][c][s] bf16 (s=i*64+d) ->
// out[b][d*128+i][c] bf16
// ---------------------------------------------------------------------------
__global__ __launch_bounds__(256) void transpose_ao(const ushort* __restrict__ in_,
                                                    ushort* __restrict__ out)
{
    __shared__ float T[64][65];
    const int p0 = blockIdx.x * 64;
    const int c0 = blockIdx.y * 64;
    const int b  = blockIdx.z;
    const int t  = threadIdx.x;
    const int rc = t >> 4;
    const int rp = (t & 15) * 4;

    #pragma unroll
    for (int pass = 0; pass < 4; ++pass) {
        const int c = pass * 16 + rc;
        const size_t base = ((size_t)(b * CH + c0 + c)) * PPB + p0 + rp;
        const ushort4 v = *(const ushort4*)(in_ + base);
        T[c][rp]     = bf2f(v.x); T[c][rp + 1] = bf2f(v.y);
        T[c][rp + 2] = bf2f(v.z); T[c][rp + 3] = bf2f(v.w);
    }
    __syncthreads();
    #pragma unroll
    for (int pass = 0; pass < 4; ++pass) {
        const int p = pass * 16 + rc;                    // tile-local s
        const int prow = p * 128 + blockIdx.x;           // s=i*64+d -> p=d*128+i
        ushort4 o;
        o.x = f2bf(T[rp + 0][p]); o.y = f2bf(T[rp + 1][p]);
        o.z = f2bf(T[rp + 2][p]); o.w = f2bf(T[rp + 3][p]);
        *(ushort4*)(out + ((size_t)(b * PPB + prow)) * CH + c0 + rp) = o;
    }
}

// ---------------------------------------------------------------------------
// 128x128 bf16 MFMA GEMM, BK=64, 4 waves (2x2), wave tile 64x64, 16x16x32.
// R10: 64 KB LDS dbuf -> 2 blocks/CU (m114 cross-block overlap absorbs the
// barrier drain that 256²'s 1-block/CU could not hide). Same zero-conflict
// layout as r7: rows of 128B, chunk^(row&7) XOR swizzle both-sides; same
// r7 schedule: early stageA -> counted vmcnt(4) -> barrier -> ds_reads with
// stageB interleaved -> lgkmcnt(0) -> setprio MFMA (kk-outer) -> barrier.
// IS_WO=0: 3072 blocks, g=0:q(lidT,remap) 1:k(camT,remap) 2:v(camT,linear).
// IS_WO=1: 1024 blocks, g=3, B linear, f32 gelu out. W3 = weight base (ws).
// ---------------------------------------------------------------------------
template <int IS_WO>
__global__ __launch_bounds__(256, 2) void gemm128(const ushort* __restrict__ W3,
                                                  const ushort* __restrict__ lidT,
                                                  const ushort* __restrict__ camT,
                                                  void* __restrict__ outp)
{
    __shared__ __align__(16) ushort sh[32768];  // bytes [0,32K): A dbuf; [32K,64K): B dbuf
    char* shb = (char*)sh;

    const int bid = blockIdx.x;
    int g, bm, bn;
    if (IS_WO) {
        const int sid = (bid & 7) * 128 + (bid >> 3);   // 1024 % 8 == 0, bijective
        g = 3; bm = sid & 7; bn = sid >> 3;
    } else {
        const int sid = (bid & 7) * 384 + (bid >> 3);   // 3072 % 8 == 0, bijective
        g = sid >> 10; const int r = sid & 1023; bm = r & 7; bn = r >> 3;
    }
    const int m0  = bm * 128;
    const int b   = bn >> 6;                // 128 n-tiles, 64 per batch
    const int i0  = (bn & 63) * 2;          // q/k remap: 2 i-values per 128-tile
    const int n0  = bn * 128;               // linear B row base
    const int p0  = (bn & 63) * 128;
    const ushort* A  = W3 + (size_t)g * (1u << 20);
    const ushort* Bt = (g == 0) ? lidT : camT;   // IS_WO: camT param carries aoT
    const bool remap = (!IS_WO) && (g < 2);

    const int tid = threadIdx.x;
    const int w   = tid >> 6;
    const int l   = tid & 63;
    const int wr  = w >> 1;       // 0..1  M half
    const int wc  = w & 1;        // 0..1  N half
    const int hi  = l >> 4;
    const int fr  = l & 15;

    // stage one 16KB tile (A or B) of K-tile kt into buffer buf.
    // dest linear; source chunk pre-swizzled: LDS[row][slot s] holds global
    // chunk s^(row&7)  (involution; read applies the same XOR). Rows = 128B.
    auto stageA = [&](int buf, int kt) {
        const int k0 = kt * 64;
        #pragma unroll
        for (int ld = 0; ld < 4; ++ld) {
            const int c  = w * 4 + ld;                 // chunk 0..15 (8 rows each)
            const int rt = c * 8 + (l >> 3);
            const int kc = ((l & 7) ^ (rt & 7)) << 3;
            gload16(A + (size_t)(m0 + rt) * CH + k0 + kc,
                    &shb[buf * 16384 + c * 1024]);
        }
    };
    auto stageB = [&](int buf, int kt) {
        const int k0 = kt * 64;
        #pragma unroll
        for (int ld = 0; ld < 4; ++ld) {
            const int c  = w * 4 + ld;
            const int rt = c * 8 + (l >> 3);
            const int kc = ((l & 7) ^ (rt & 7)) << 3;
            size_t brow;
            if (remap) brow = (size_t)b * PPB + (size_t)(rt & 63) * 128 + i0 + (rt >> 6);
            else       brow = (size_t)(n0 + rt);
            gload16(Bt + brow * CH + k0 + kc,
                    &shb[32768 + buf * 16384 + c * 1024]);
        }
    };

    f32x4 acc[4][4];
    #pragma unroll
    for (int i = 0; i < 4; ++i)
        #pragma unroll
        for (int j = 0; j < 4; ++j) acc[i][j] = (f32x4)(0.0f);

    // prologue: tile 0 (8 vmem instructions)
    stageA(0, 0); stageB(0, 0);

    for (int kt = 0; kt < 16; ++kt) {
        const int buf = kt & 1, nxt = buf ^ 1;
        // early-issue next A; counted wait leaves it in flight across barriers
        // (T4: never drain mid-loop). Outstanding: 8 (tile kt) + 4 -> wait to 4.
        if (kt < 15) {
            stageA(nxt, kt + 1);
            __builtin_amdgcn_sched_barrier(0);
            asm volatile("s_waitcnt vmcnt(4)" ::: "memory");  // tile kt resident
        } else {
            __builtin_amdgcn_sched_barrier(0);
            asm volatile("s_waitcnt vmcnt(0)" ::: "memory");
        }
        __builtin_amdgcn_s_barrier();           // all waves see tile kt in LDS
        __builtin_amdgcn_sched_barrier(0);
        const int Ab = buf * 16384, Bb = 32768 + buf * 16384;

        short8 aq[4][2], bq[4][2];
        #pragma unroll
        for (int fm = 0; fm < 4; ++fm) {
            const int row = wr * 64 + fm * 16 + fr;
            #pragma unroll
            for (int kk = 0; kk < 2; ++kk)
                aq[fm][kk] = *(const short8*)&shb[Ab + row * 128 +
                    ((((kk << 2) + hi) ^ (row & 7)) << 4)];
        }
        #pragma unroll
        for (int fn = 0; fn < 4; ++fn) {
            const int row = wc * 64 + fn * 16 + fr;
            #pragma unroll
            for (int kk = 0; kk < 2; ++kk)
                bq[fn][kk] = *(const short8*)&shb[Bb + row * 128 +
                    ((((kk << 2) + hi) ^ (row & 7)) << 4)];
        }
        // interleave next-B issue while ds_reads are in flight
        if (kt < 15) stageB(nxt, kt + 1);
        __builtin_amdgcn_sched_barrier(0);
        asm volatile("s_waitcnt lgkmcnt(0)" ::: "memory");
        __builtin_amdgcn_sched_barrier(0);

        __builtin_amdgcn_s_setprio(1);
        #pragma unroll
        for (int kk = 0; kk < 2; ++kk)          // kk-outer: 16 independent MFMAs
            #pragma unroll
            for (int fm = 0; fm < 4; ++fm)
                #pragma unroll
                for (int fn = 0; fn < 4; ++fn)
                    acc[fm][fn] = __builtin_amdgcn_mfma_f32_16x16x32_bf16(
                        aq[fm][kk], bq[fn][kk], acc[fm][fn], 0, 0, 0);
        __builtin_amdgcn_s_setprio(0);

        // my ds_reads already drained (lgkmcnt 0 above); end-of-tile barrier
        // makes buf safe for tile kt+2's stages (WAR).
        __builtin_amdgcn_sched_barrier(0);
        __builtin_amdgcn_s_barrier();
        __builtin_amdgcn_sched_barrier(0);
    }

    // epilogue: C/D col=fr, row=hi*4+r (m89-verified)
    #pragma unroll
    for (int fm = 0; fm < 4; ++fm)
        #pragma unroll
        for (int fn = 0; fn < 4; ++fn)
            #pragma unroll
            for (int r = 0; r < 4; ++r) {
                const int m = m0 + wr * 64 + fm * 16 + hi * 4 + r;
                const int n = wc * 64 + fn * 16 + fr;
                const float vv = acc[fm][fn][r];
                const size_t off = (size_t)b * CH * PPB + (size_t)m * PPB + p0 + n;
                if (IS_WO) {
                    ((float*)outp)[off] = 0.5f * vv * (1.0f + erff(vv * 0.70710678118654752f));
                } else {
                    ((ushort*)outp)[(size_t)g * ((size_t)16 << 20) + off] = f2bf(vv);
                }
            }
}

// ---------------------------------------------------------------------------
// MFMA attention, one (b,h) per block, 4 waves (unchanged from rounds 3-7).
// ---------------------------------------------------------------------------
__global__ __launch_bounds__(256, 2) void attn_mfma(const ushort* __restrict__ qt,
                                                    const ushort* __restrict__ kt,
                                                    const ushort* __restrict__ vn,
                                                    ushort* __restrict__ ot)
{
    __shared__ ushort Qs[8192];
    __shared__ ushort Ks[8192];
    __shared__ ushort Vs[8192];
    __shared__ ushort Ps[16384];

    const int bh  = blockIdx.x;
    const int tid = threadIdx.x;
    const int w   = tid >> 6;
    const int l   = tid & 63;
    const int hi  = l >> 4;
    const int fr  = l & 15;
    const size_t base = (size_t)bh * 8192;

    {
        const int lr = l >> 3, lb = l & 7;
        const int vr = l >> 4, vbk = l & 15;
        #pragma unroll
        for (int q = 0; q < 4; ++q) {
            const int ch = w * 4 + q;
            const int i  = ch * 8 + lr;
            gload16(qt + base + i * 64 + ((lb ^ (i & 7)) << 3), &Qs[ch * 512]);
            gload16(kt + base + i * 64 + ((lb ^ (i & 7)) << 3), &Ks[ch * 512]);
            const int d  = ch * 4 + vr;
            gload16(vn + base + d * 128 + ((vbk ^ (d & 15)) << 3), &Vs[ch * 512]);
        }
    }
    __syncthreads();

    const int i0w = w * 32;
    f32x4 accS[2][8];
    #pragma unroll
    for (int a = 0; a < 2; ++a)
        #pragma unroll
        for (int bjj = 0; bjj < 8; ++bjj) accS[a][bjj] = (f32x4)(0.0f);

    #pragma unroll
    for (int kk = 0; kk < 2; ++kk) {
        const int blk = kk * 4 + hi;
        short8 aq[2];
        #pragma unroll
        for (int fm = 0; fm < 2; ++fm) {
            const int i = i0w + fm * 16 + fr;
            aq[fm] = *(const short8*)&Qs[i * 64 + ((blk ^ (i & 7)) << 3)];
        }
        #pragma unroll
        for (int fn = 0; fn < 8; ++fn) {
            const int j = fn * 16 + fr;
            const short8 bk = *(const short8*)&Ks[j * 64 + ((blk ^ (j & 7)) << 3)];
            #pragma unroll
            for (int fm = 0; fm < 2; ++fm)
                accS[fm][fn] = __builtin_amdgcn_mfma_f32_16x16x32_bf16(
                    aq[fm], bk, accS[fm][fn], 0, 0, 0);
        }
    }

    const float CS = 0.125f * 1.44269504088896341f;
    #pragma unroll
    for (int fm = 0; fm < 2; ++fm) {
        #pragma unroll
        for (int r = 0; r < 4; ++r) {
            float mx = accS[fm][0][r];
            #pragma unroll
            for (int fn = 1; fn < 8; ++fn) mx = fmaxf(mx, accS[fm][fn][r]);
            #pragma unroll
            for (int msk = 1; msk <= 8; msk <<= 1) mx = fmaxf(mx, __shfl_xor(mx, msk, 64));
            float e[8], sum = 0.f;
            #pragma unroll
            for (int fn = 0; fn < 8; ++fn) {
                e[fn] = exp2f((accS[fm][fn][r] - mx) * CS);
                sum += e[fn];
            }
            #pragma unroll
            for (int msk = 1; msk <= 8; msk <<= 1) sum += __shfl_xor(sum, msk, 64);
            const float is = 1.0f / sum;
            const int i = i0w + fm * 16 + hi * 4 + r;
            #pragma unroll
            for (int fn = 0; fn < 8; ++fn) {
                const int j = fn * 16 + fr;
                Ps[i * 128 + (((j >> 3) ^ (i & 15)) << 3) + (j & 7)] = f2bf(e[fn] * is);
            }
        }
    }

    f32x4 accO[2][4];
    #pragma unroll
    for (int a = 0; a < 2; ++a)
        #pragma unroll
        for (int bjj = 0; bjj < 4; ++bjj) accO[a][bjj] = (f32x4)(0.0f);

    #pragma unroll
    for (int ks2 = 0; ks2 < 4; ++ks2) {
        const int blk = ks2 * 4 + hi;
        short8 ap[2];
        #pragma unroll
        for (int fm = 0; fm < 2; ++fm) {
            const int i = i0w + fm * 16 + fr;
            ap[fm] = *(const short8*)&Ps[i * 128 + ((blk ^ (i & 15)) << 3)];
        }
        #pragma unroll
        for (int fn2 = 0; fn2 < 4; ++fn2) {
            const int d = fn2 * 16 + fr;
            const short8 bv = *(const short8*)&Vs[d * 128 + ((blk ^ (d & 15)) << 3)];
            #pragma unroll
            for (int fm = 0; fm < 2; ++fm)
                accO[fm][fn2] = __builtin_amdgcn_mfma_f32_16x16x32_bf16(
                    ap[fm], bv, accO[fm][fn2], 0, 0, 0);
        }
    }

    #pragma unroll
    for (int fm = 0; fm < 2; ++fm)
        #pragma unroll
        for (int fn2 = 0; fn2 < 4; ++fn2)
            #pragma unroll
            for (int r = 0; r < 4; ++r) {
                const int i = i0w + fm * 16 + hi * 4 + r;
                const int d = fn2 * 16 + fr;
                ot[base + i * 64 + d] = f2bf(accO[fm][fn2][r]);
            }
}

// ---------------------------------------------------------------------------
extern "C" void kernel_launch(void* const* d_in, const int* in_sizes, int n_in,
                              void* d_out, int out_size, void* d_ws, size_t ws_size,
                              hipStream_t stream)
{
    const float* lidar = (const float*)d_in[0];
    const float* cam   = (const float*)d_in[1];
    const float* Wq    = (const float*)d_in[2];
    const float* Wk    = (const float*)d_in[3];
    const float* Wv    = (const float*)d_in[4];
    const float* Wo    = (const float*)d_in[5];

    ushort* ws = (ushort*)d_ws;
    const size_t M1 = (size_t)1 << 20;
    const size_t TT = (size_t)16 << 20;
    ushort* lidT = ws + 4 * M1;
    ushort* camT = lidT + TT;
    ushort* qb   = camT + TT;   // q_t [b][c][i][d]; attn overwrites with O_t
    ushort* aoT  = lidT;        // reuse (lidT dead after q GEMM)

    prep<<<dim3(10240), dim3(256), 0, stream>>>(lidar, cam, Wq, Wk, Wv, Wo, ws, lidT, camT);

    gemm128<0><<<dim3(3072), dim3(256), 0, stream>>>(ws, lidT, camT, qb);

    attn_mfma<<<dim3(2048), dim3(256), 0, stream>>>(qb, qb + TT, qb + 2 * TT, qb);

    transpose_ao<<<dim3(128, 16, 2), dim3(256), 0, stream>>>(qb, aoT);

    gemm128<1><<<dim3(1024), dim3(256), 0, stream>>>(ws, aoT, aoT, (float*)d_out);
}